// Round 4
// baseline (239.691 us; speedup 1.0000x reference)
//
#include <hip/hip_runtime.h>
#include <cstdint>
#include <cstddef>

#define BB   32
#define NN   1024
#define FIN  128
#define FOUT 128

typedef __attribute__((ext_vector_type(8))) short bf16x8;
typedef __attribute__((ext_vector_type(4))) float f32x4;

__device__ __forceinline__ unsigned int f2bf(float f) {
    union { float f; unsigned int u; } v; v.f = f;
    unsigned int u = v.u;
    return (u + 0x7FFFu + ((u >> 16) & 1u)) >> 16;   // RNE fp32 -> bf16
}
__device__ __forceinline__ unsigned int pack2(float a, float b) {
    return f2bf(a) | (f2bf(b) << 16);
}

// ---------------------------------------------------------------------------
// Kernel 1: Yt[b][o][m] = sum_f node[b][m][f] * W[o][f]  (bf16, [B][FOUT][NN])
// (unchanged — measured ~3 us, not the target)
// ---------------------------------------------------------------------------
__global__ __launch_bounds__(256) void y_kernel(const float* __restrict__ node,
                                                const float* __restrict__ W,
                                                unsigned short* __restrict__ Yt) {
    __shared__ unsigned short Wlds[128 * 136];
    __shared__ unsigned short Nlds[64 * 136];

    const int tid = threadIdx.x;
    const int bid = blockIdx.x;
    const int b   = bid >> 4;
    const int m0  = (bid & 15) * 64;

    #pragma unroll
    for (int i = 0; i < 16; ++i) {
        const int idx = i * 256 + tid;
        const int row = idx >> 5;
        const int c   = (idx & 31) * 4;
        float4 v = ((const float4*)W)[idx];
        uint2 p; p.x = pack2(v.x, v.y); p.y = pack2(v.z, v.w);
        *(uint2*)&Wlds[row * 136 + c] = p;
    }
    {
        const float* base = node + ((size_t)b * NN + m0) * FIN;
        #pragma unroll
        for (int i = 0; i < 8; ++i) {
            const int idx = i * 256 + tid;
            const int row = idx >> 5;
            const int c   = (idx & 31) * 4;
            float4 v = *(const float4*)(base + row * FIN + c);
            uint2 p; p.x = pack2(v.x, v.y); p.y = pack2(v.z, v.w);
            *(uint2*)&Nlds[row * 136 + c] = p;
        }
    }
    __syncthreads();

    const int w = tid >> 6, lane = tid & 63;
    const int wo = w * 32;
    const int lcol = lane & 15, lk = (lane >> 4) * 8;

    f32x4 acc[2][4] = {};
    #pragma unroll
    for (int kc = 0; kc < 4; ++kc) {
        const int kof = kc * 32 + lk;
        bf16x8 a[2], bb[4];
        #pragma unroll
        for (int mi = 0; mi < 2; ++mi)
            a[mi] = *(const bf16x8*)&Wlds[(wo + mi*16 + lcol) * 136 + kof];
        #pragma unroll
        for (int ni = 0; ni < 4; ++ni)
            bb[ni] = *(const bf16x8*)&Nlds[(ni*16 + lcol) * 136 + kof];
        #pragma unroll
        for (int mi = 0; mi < 2; ++mi)
            #pragma unroll
            for (int ni = 0; ni < 4; ++ni)
                acc[mi][ni] = __builtin_amdgcn_mfma_f32_16x16x32_bf16(
                    a[mi], bb[ni], acc[mi][ni], 0, 0, 0);
    }
    __syncthreads();

    unsigned short* Ylds = Wlds;
    const int rq = (lane >> 4) * 4;
    #pragma unroll
    for (int mi = 0; mi < 2; ++mi)
        #pragma unroll
        for (int ni = 0; ni < 4; ++ni)
            #pragma unroll
            for (int r = 0; r < 4; ++r) {
                const int o = wo + mi * 16 + rq + r;
                const int m = ni * 16 + lcol;
                Ylds[o * 72 + m] = (unsigned short)f2bf(acc[mi][ni][r]);
            }
    __syncthreads();

    {
        const int oq = tid >> 3, c = (tid & 7) * 8;
        #pragma unroll
        for (int j = 0; j < 4; ++j) {
            const int o = oq + 32 * j;
            uint4 v = *(const uint4*)&Ylds[o * 72 + c];
            *(uint4*)(Yt + ((size_t)b * FOUT + o) * NN + m0 + c) = v;
        }
    }
}

// ---------------------------------------------------------------------------
// Kernel 2 v6: reg-staged, padded-LDS, 1-barrier/step double buffer.
// Round-3 post-mortem: 16B-granular source swizzle on global_load_lds
// defeats lane coalescing -> ~25M independent 16B L2 requests/dispatch ->
// request-rate bound at ~1.1 TB/s (round-0 single-buffer == round-3 double-
// buffer == ~70-78 us confirms it's not latency). Meanwhile measured bank-
// conflict cost was only ~2%. So: make global loads perfectly lane-linear
// (full 64/128B line coalescing), stage via registers, ds_write_b128 into
// PADDED LDS (pads legal for per-lane writes, unlike global_load_lds):
//   A [32][36 fp32]  -> frag-read bank group (R+2q)%8 : 8 groups x2 = free
//   B [128][40 bf16] -> frag-read bank group (5o+q)%8 : 8 groups x2 = free
// Pipeline per step (raw s_barrier, no vmcnt(0) on global in loop):
//   ds_write step t+1 (regs loaded last iter; compiler waits its vmcnt)
//   -> issue global loads step t+2 -> compute step t from other buffer
//   -> lgkmcnt(0) + s_barrier.  Loads get a full iteration to fly.
// Fragment k-indices / pack / rowsum / epilogue byte-identical to passing
// kernels. LDS 29.7 KB (2 bufs), grid 1024 = 4 blocks/CU fully resident.
// ---------------------------------------------------------------------------
#define ABYTES 4608            // 32 * 36 fp32 * 4
#define BBYTES 10240           // 128 * 40 bf16 * 2
#define BUFB   (ABYTES + BBYTES)   // 14848

__global__ __launch_bounds__(256, 4) void gcn_kernel(const float* __restrict__ adj,
                                                     const unsigned short* __restrict__ Yt,
                                                     const float* __restrict__ bias,
                                                     float* __restrict__ out) {
    __shared__ __align__(16) char smem[2 * BUFB];

    const int tid  = threadIdx.x;
    const int lane = tid & 63;
    const int w    = tid >> 6;

    const int raw = blockIdx.x;
    const int bid = (raw & 7) * 128 + (raw >> 3);    // XCD-contiguous, bijective
    const int b   = bid >> 5;
    const int n0  = (bid & 31) * 32;

    const int lcol = lane & 15, q = lane >> 4;
    const int wm = (w & 1) * 16;                     // row half  (0 / 16)
    const int wn = (w >> 1) * 64;                    // col half  (0 / 64)

    // ---- staging addresses (global linear, LDS padded) ----
    // A: 32 rows x 32 fp32 / step. Wave w: rows w*8..w*8+7.
    //    lane l -> row w*8+(l>>3), 16B chunk l&7  (8 lanes = 128B line)
    const int grA = w * 8 + (lane >> 3);
    const int gcA = lane & 7;
    const float* aSrc = adj + ((size_t)(b * NN + n0 + grA)) * NN + gcA * 4;
    const int aWoff = (grA * 36 + gcA * 4) * 4;      // padded stride 36 fp32

    // B: 128 rows x 32 bf16 / step. Wave w, j=0,1: rows (w*2+j)*16 + (l>>2).
    //    lane l -> 16B chunk l&3  (4 lanes = 64B line)
    const unsigned short* bSrc[2];
    int bWoff[2];
    #pragma unroll
    for (int j = 0; j < 2; ++j) {
        const int o  = (w * 2 + j) * 16 + (lane >> 2);
        const int kc = lane & 3;
        bSrc[j]  = Yt + ((size_t)(b * FOUT + o)) * NN + kc * 8;
        bWoff[j] = ABYTES + o * 80 + kc * 16;        // padded stride 40 bf16
    }

    // ---- fragment read byte-offsets within a buffer ----
    const int R = wm + lcol;
    const int offA0 = (R * 36 + q * 8) * 4;          // 8 fp32 = 2x b128
    int offB[4];
    #pragma unroll
    for (int ni = 0; ni < 4; ++ni) {
        const int o = wn + ni * 16 + lcol;
        offB[ni] = ABYTES + o * 80 + q * 16;
    }

    f32x4 acc[4] = {};
    float rsum = 0.f;

    float4 ra; uint4 rb0, rb1;

    #define GLOAD(s)                                                       \
        do {                                                               \
            ra  = *(const float4*)(aSrc    + (s) * 32);                    \
            rb0 = *(const uint4*)(bSrc[0] + (s) * 32);                     \
            rb1 = *(const uint4*)(bSrc[1] + (s) * 32);                     \
        } while (0)

    #define DSWRITE(buf)                                                   \
        do {                                                               \
            char* base = smem + (buf) * BUFB;                              \
            *(float4*)(base + aWoff)    = ra;                              \
            *(uint4*)(base + bWoff[0]) = rb0;                              \
            *(uint4*)(base + bWoff[1]) = rb1;                              \
        } while (0)

    #define COMPUTE(buf)                                                   \
        do {                                                               \
            const char* base = smem + (buf) * BUFB;                        \
            const float4 f0 = *(const float4*)(base + offA0);              \
            const float4 f1 = *(const float4*)(base + offA0 + 16);         \
            rsum += ((f0.x + f0.y) + (f0.z + f0.w))                        \
                  + ((f1.x + f1.y) + (f1.z + f1.w));                       \
            uint4 pk;                                                      \
            pk.x = pack2(f0.x, f0.y); pk.y = pack2(f0.z, f0.w);            \
            pk.z = pack2(f1.x, f1.y); pk.w = pack2(f1.z, f1.w);            \
            const bf16x8 a = *(const bf16x8*)&pk;                          \
            _Pragma("unroll")                                              \
            for (int ni = 0; ni < 4; ++ni) {                               \
                const bf16x8 bbf = *(const bf16x8*)(base + offB[ni]);      \
                acc[ni] = __builtin_amdgcn_mfma_f32_16x16x32_bf16(         \
                    a, bbf, acc[ni], 0, 0, 0);                             \
            }                                                              \
        } while (0)

    // prologue: stage step 0 into buf0, prefetch step 1 into regs
    GLOAD(0);
    DSWRITE(0);
    GLOAD(1);
    asm volatile("s_waitcnt lgkmcnt(0)" ::: "memory");
    __builtin_amdgcn_s_barrier();

    // 32 K-steps; regs hold step t+1 at top of iter t
    #pragma unroll 2
    for (int t = 0; t < 32; ++t) {
        const int cur = t & 1, nxt = cur ^ 1;
        if (t < 31) DSWRITE(nxt);        // step t+1 -> other buffer (safe:
                                          //   its readers finished pre-barrier)
        if (t < 30) GLOAD(t + 2);         // flies under compute + barrier
        COMPUTE(cur);
        if (t < 31) {
            asm volatile("s_waitcnt lgkmcnt(0)" ::: "memory");
            __builtin_amdgcn_s_barrier();
        }
    }
    #undef GLOAD
    #undef DSWRITE
    #undef COMPUTE

    // full row sums: lanes sharing lcol hold disjoint k-slices of row wm+lcol
    rsum += __shfl_xor(rsum, 16);
    rsum += __shfl_xor(rsum, 32);

    // D layout: col = lane&15 (o), row-in-tile = q*4 + r.
    // 1/rowsum for row wm+(rq+r): lane rq+r holds it (lcol = rq+r).
    const int rq = q * 4;
    float sc[4];
    #pragma unroll
    for (int r = 0; r < 4; ++r) sc[r] = 1.0f / __shfl(rsum, rq + r);

    float* outB = out + ((size_t)(b * NN + n0 + wm)) * FOUT;
    #pragma unroll
    for (int ni = 0; ni < 4; ++ni) {
        const float bc = bias[wn + ni * 16 + lcol];
        #pragma unroll
        for (int r = 0; r < 4; ++r) {
            float v = acc[ni][r] * sc[r] + bc;
            v = (v >= 0.f) ? v : 0.01f * v;
            outB[(size_t)(rq + r) * FOUT + wn + ni * 16 + lcol] = v;
        }
    }
}

extern "C" void kernel_launch(void* const* d_in, const int* in_sizes, int n_in,
                              void* d_out, int out_size, void* d_ws, size_t ws_size,
                              hipStream_t stream) {
    const float* node = (const float*)d_in[0];   // [32,1024,128]
    const float* adj  = (const float*)d_in[1];   // [32,1024,1024]
    const float* W    = (const float*)d_in[2];   // [128,128]
    const float* bias = (const float*)d_in[3];   // [128]
    float* out = (float*)d_out;                  // [32,1024,128] fp32
    unsigned short* Yt = (unsigned short*)d_ws;  // [32,128,1024] bf16 = 8 MiB

    hipLaunchKernelGGL(y_kernel,   dim3(512),  dim3(256), 0, stream, node, W, Yt);
    hipLaunchKernelGGL(gcn_kernel, dim3(1024), dim3(256), 0, stream, adj, Yt, bias, out);
}